// Round 3
// baseline (2233.348 us; speedup 1.0000x reference)
//
#include <hip/hip_runtime.h>

// LSTM, B=512 x T=1024, H=100, input_size=1.
// Persistent-RNN: one block per 2 batches (grid=256 -> 1 block/CU, single pass).
// Thread r<400 holds W_hh row r in VGPRs (25 float4); h broadcast via LDS.
// R2 bug: compiler REMATERIALIZED the weight loads (const __restrict__ global
// loads are re-issuable) and re-read W_hh from L2 every timestep (VGPR=92,
// ~1.2ms of L2 traffic). Fix: asm volatile barrier on each loaded value makes
// it opaque -> must stay in VGPRs. __launch_bounds__(448,1) gives the 512-reg
// budget so it won't spill to scratch.

#define HID   100
#define H4    25     // HID/4
#define FOURH 400
#define TLEN  1024
#define BLOCK 448    // 7 waves; threads 0..399 own gate rows

__global__ __launch_bounds__(BLOCK, 1) void lstm_persist3(
    const float* __restrict__ input,   // [B, T]
    const float* __restrict__ W_ih,    // [4H]
    const float* __restrict__ W_hh,    // [4H, H]
    const float* __restrict__ b_ih,    // [4H]
    const float* __restrict__ b_hh,    // [4H]
    const float* __restrict__ W_out,   // [H]
    const float* __restrict__ b_out,   // [1]
    float* __restrict__ out)           // [B, T]
{
    const int b0  = blockIdx.x * 2;    // this block owns batches b0, b0+1
    const int tid = threadIdx.x;

    __shared__ float4 h0_4[H4];        // h for batch b0 (16B-aligned)
    __shared__ float4 h1_4[H4];        // h for batch b0+1
    __shared__ float  g0_s[FOURH];
    __shared__ float  g1_s[FOURH];
    __shared__ float  in0_s[TLEN];
    __shared__ float  in1_s[TLEN];

    // Stage both input rows (8 KB), coalesced.
    for (int i = tid; i < TLEN; i += BLOCK) {
        in0_s[i] = input[(b0 + 0) * TLEN + i];
        in1_s[i] = input[(b0 + 1) * TLEN + i];
    }

    // Pin this thread's recurrent-weight row in registers — UNCONDITIONAL
    // load (clamped row), then an asm barrier per element so the compiler
    // cannot rematerialize the loads inside the t-loop.
    const int r = (tid < FOURH) ? tid : 0;
    float4 w[H4];
    {
        const float4* wrow = (const float4*)(W_hh + r * HID);  // 400 B rows: 16B-aligned
        #pragma unroll
        for (int k = 0; k < H4; ++k) {
            float4 v = wrow[k];
            asm volatile("" : "+v"(v.x), "+v"(v.y), "+v"(v.z), "+v"(v.w));
            w[k] = v;
        }
    }
    const float wih  = W_ih[r];
    const float bias = b_ih[r] + b_hh[r];

    // Output-projection weights for the two reduction waves (tid<128).
    float wo0 = 0.f, wo1 = 0.f, bo = 0.f;
    if (tid < 128) {
        const int l = tid & 63;              // l in 0..63, all < HID
        wo0 = W_out[l];
        wo1 = (l < HID - 64) ? W_out[64 + l] : 0.f;
        bo  = b_out[0];
    }

    float c = 0.f;                       // cell state (tid<200: one per batch-element)
    if (tid < HID) { ((float*)h0_4)[tid] = 0.f; ((float*)h1_4)[tid] = 0.f; }
    __syncthreads();

    for (int t = 0; t < TLEN; ++t) {
        // ---- Phase A: dual-batch dot products against register-resident row
        if (tid < FOURH) {
            float base0 = fmaf(in0_s[t], wih, bias);
            float base1 = fmaf(in1_s[t], wih, bias);
            float a0 = 0.f, a1 = 0.f, a2 = 0.f, a3 = 0.f;
            float d0 = 0.f, d1 = 0.f, d2 = 0.f, d3 = 0.f;
            #pragma unroll
            for (int k = 0; k < H4; ++k) {
                float4 ha = h0_4[k];     // wave-uniform address -> LDS broadcast
                float4 hb = h1_4[k];
                float4 wk = w[k];
                a0 = fmaf(ha.x, wk.x, a0);
                a1 = fmaf(ha.y, wk.y, a1);
                a2 = fmaf(ha.z, wk.z, a2);
                a3 = fmaf(ha.w, wk.w, a3);
                d0 = fmaf(hb.x, wk.x, d0);
                d1 = fmaf(hb.y, wk.y, d1);
                d2 = fmaf(hb.z, wk.z, d2);
                d3 = fmaf(hb.w, wk.w, d3);
            }
            g0_s[tid] = base0 + ((a0 + a1) + (a2 + a3));
            g1_s[tid] = base1 + ((d0 + d1) + (d2 + d3));
        }
        __syncthreads();

        // ---- Phase B: pointwise LSTM cell, 200 threads (100 per batch)
        if (tid < 2 * HID) {
            const int   j  = (tid < HID) ? tid : tid - HID;
            const float* g = (tid < HID) ? g0_s : g1_s;
            float*       h = (tid < HID) ? (float*)h0_4 : (float*)h1_4;
            float ig = g[j];
            float fg = g[HID + j];
            float gg = g[2 * HID + j];
            float og = g[3 * HID + j];
            float is = 1.f / (1.f + __expf(-ig));
            float fs = 1.f / (1.f + __expf(-fg));
            float os = 1.f / (1.f + __expf(-og));
            float gt = 1.f - 2.f / (__expf(2.f * gg) + 1.f);   // stable tanh
            c = fmaf(fs, c, is * gt);
            float th = 1.f - 2.f / (__expf(2.f * c) + 1.f);
            h[j] = os * th;
        }
        __syncthreads();

        // ---- Phase C: out[t] = dot(h, W_out)+b_out; wave0->batch0, wave1->batch1
        if (tid < 128) {
            const int    l = tid & 63;
            const float* h = (tid < 64) ? (const float*)h0_4 : (const float*)h1_4;
            float p = h[l] * wo0;
            if (l < HID - 64) p = fmaf(h[64 + l], wo1, p);
            #pragma unroll
            for (int off = 32; off > 0; off >>= 1)
                p += __shfl_down(p, off);
            if (l == 0) out[(b0 + (tid >> 6)) * TLEN + t] = p + bo;
        }
        // No barrier here: h is re-written only after the next Phase-A barrier,
        // so Phase C(t) overlaps Phase A(t+1) reads (both read-only on h).
    }
}

extern "C" void kernel_launch(void* const* d_in, const int* in_sizes, int n_in,
                              void* d_out, int out_size, void* d_ws, size_t ws_size,
                              hipStream_t stream) {
    const float* input = (const float*)d_in[0];
    const float* W_ih  = (const float*)d_in[1];
    const float* W_hh  = (const float*)d_in[2];
    const float* b_ih  = (const float*)d_in[3];
    const float* b_hh  = (const float*)d_in[4];
    const float* W_out = (const float*)d_in[5];
    const float* b_out = (const float*)d_in[6];
    float* out = (float*)d_out;

    const int B = in_sizes[0] / TLEN;  // 512
    lstm_persist3<<<B / 2, BLOCK, 0, stream>>>(input, W_ih, W_hh, b_ih, b_hh,
                                               W_out, b_out, out);
}

// Round 4
// 1961.266 us; speedup vs baseline: 1.1387x; 1.1387x over previous
//
#include <hip/hip_runtime.h>

// LSTM, B=512 x T=1024, H=100, input_size=1.
// Persistent-RNN: one block per 2 batches (grid=256 -> 1 block/CU, single pass).
// Thread r<400 holds W_hh row r in VGPRs (25 float4); h broadcast via LDS.
//
// R2 bug: compiler rematerialized the const weight loads into the t-loop.
//   Fix: asm volatile value barriers (kept below).
// R3 bug: register allocator targeted 4 waves/EU -> capped VGPR at 128 and
//   spilled w[] to scratch (VGPR_Count=128, 42ms cold dispatch).
//   Fix: amdgpu_waves_per_eu(2,2) — plan for exactly 2 waves/EU (the physical
//   occupancy of a 7-wave block at 1 block/CU) -> 256-reg budget, no spill.

#define HID   100
#define H4    25     // HID/4
#define FOURH 400
#define TLEN  1024
#define BLOCK 448    // 7 waves; threads 0..399 own gate rows

__global__ __launch_bounds__(BLOCK)
__attribute__((amdgpu_waves_per_eu(2, 2)))
void lstm_persist4(
    const float* __restrict__ input,   // [B, T]
    const float* __restrict__ W_ih,    // [4H]
    const float* __restrict__ W_hh,    // [4H, H]
    const float* __restrict__ b_ih,    // [4H]
    const float* __restrict__ b_hh,    // [4H]
    const float* __restrict__ W_out,   // [H]
    const float* __restrict__ b_out,   // [1]
    float* __restrict__ out)           // [B, T]
{
    const int b0  = blockIdx.x * 2;    // this block owns batches b0, b0+1
    const int tid = threadIdx.x;

    __shared__ float4 h0_4[H4];        // h for batch b0 (16B-aligned)
    __shared__ float4 h1_4[H4];        // h for batch b0+1
    __shared__ float  g0_s[FOURH];
    __shared__ float  g1_s[FOURH];
    __shared__ float  in0_s[TLEN];
    __shared__ float  in1_s[TLEN];

    // Stage both input rows (8 KB), coalesced.
    for (int i = tid; i < TLEN; i += BLOCK) {
        in0_s[i] = input[(b0 + 0) * TLEN + i];
        in1_s[i] = input[(b0 + 1) * TLEN + i];
    }

    // Pin this thread's recurrent-weight row in registers — unconditional
    // (clamped row), with per-element asm barriers so the loads cannot be
    // rematerialized inside the t-loop.
    const int r = (tid < FOURH) ? tid : 0;
    float4 w[H4];
    {
        const float4* wrow = (const float4*)(W_hh + r * HID);  // 400 B rows: 16B-aligned
        #pragma unroll
        for (int k = 0; k < H4; ++k) {
            float4 v = wrow[k];
            asm volatile("" : "+v"(v.x), "+v"(v.y), "+v"(v.z), "+v"(v.w));
            w[k] = v;
        }
    }
    const float wih  = W_ih[r];
    const float bias = b_ih[r] + b_hh[r];

    // Output-projection weights for the two reduction waves (tid<128).
    float wo0 = 0.f, wo1 = 0.f, bo = 0.f;
    if (tid < 128) {
        const int l = tid & 63;              // l in 0..63, all < HID
        wo0 = W_out[l];
        wo1 = (l < HID - 64) ? W_out[64 + l] : 0.f;
        bo  = b_out[0];
    }

    float c = 0.f;                       // cell state (tid<200: one per batch-element)
    if (tid < HID) { ((float*)h0_4)[tid] = 0.f; ((float*)h1_4)[tid] = 0.f; }
    __syncthreads();

    for (int t = 0; t < TLEN; ++t) {
        // ---- Phase A: dual-batch dot products against register-resident row
        if (tid < FOURH) {
            float base0 = fmaf(in0_s[t], wih, bias);
            float base1 = fmaf(in1_s[t], wih, bias);
            float a0 = 0.f, a1 = 0.f, a2 = 0.f, a3 = 0.f;
            float d0 = 0.f, d1 = 0.f, d2 = 0.f, d3 = 0.f;
            #pragma unroll
            for (int k = 0; k < H4; ++k) {
                float4 ha = h0_4[k];     // wave-uniform address -> LDS broadcast
                float4 hb = h1_4[k];
                float4 wk = w[k];
                a0 = fmaf(ha.x, wk.x, a0);
                a1 = fmaf(ha.y, wk.y, a1);
                a2 = fmaf(ha.z, wk.z, a2);
                a3 = fmaf(ha.w, wk.w, a3);
                d0 = fmaf(hb.x, wk.x, d0);
                d1 = fmaf(hb.y, wk.y, d1);
                d2 = fmaf(hb.z, wk.z, d2);
                d3 = fmaf(hb.w, wk.w, d3);
            }
            g0_s[tid] = base0 + ((a0 + a1) + (a2 + a3));
            g1_s[tid] = base1 + ((d0 + d1) + (d2 + d3));
        }
        __syncthreads();

        // ---- Phase B: pointwise LSTM cell, 200 threads (100 per batch)
        if (tid < 2 * HID) {
            const int   j  = (tid < HID) ? tid : tid - HID;
            const float* g = (tid < HID) ? g0_s : g1_s;
            float*       h = (tid < HID) ? (float*)h0_4 : (float*)h1_4;
            float ig = g[j];
            float fg = g[HID + j];
            float gg = g[2 * HID + j];
            float og = g[3 * HID + j];
            float is = 1.f / (1.f + __expf(-ig));
            float fs = 1.f / (1.f + __expf(-fg));
            float os = 1.f / (1.f + __expf(-og));
            float gt = 1.f - 2.f / (__expf(2.f * gg) + 1.f);   // stable tanh
            c = fmaf(fs, c, is * gt);
            float th = 1.f - 2.f / (__expf(2.f * c) + 1.f);
            h[j] = os * th;
        }
        __syncthreads();

        // ---- Phase C: out[t] = dot(h, W_out)+b_out; wave0->batch0, wave1->batch1
        if (tid < 128) {
            const int    l = tid & 63;
            const float* h = (tid < 64) ? (const float*)h0_4 : (const float*)h1_4;
            float p = h[l] * wo0;
            if (l < HID - 64) p = fmaf(h[64 + l], wo1, p);
            #pragma unroll
            for (int off = 32; off > 0; off >>= 1)
                p += __shfl_down(p, off);
            if (l == 0) out[(b0 + (tid >> 6)) * TLEN + t] = p + bo;
        }
        // No barrier here: h is re-written only after the next Phase-A barrier,
        // so Phase C(t) overlaps Phase A(t+1) reads (both read-only on h).
    }
}

extern "C" void kernel_launch(void* const* d_in, const int* in_sizes, int n_in,
                              void* d_out, int out_size, void* d_ws, size_t ws_size,
                              hipStream_t stream) {
    const float* input = (const float*)d_in[0];
    const float* W_ih  = (const float*)d_in[1];
    const float* W_hh  = (const float*)d_in[2];
    const float* b_ih  = (const float*)d_in[3];
    const float* b_hh  = (const float*)d_in[4];
    const float* W_out = (const float*)d_in[5];
    const float* b_out = (const float*)d_in[6];
    float* out = (float*)d_out;

    const int B = in_sizes[0] / TLEN;  // 512
    lstm_persist4<<<B / 2, BLOCK, 0, stream>>>(input, W_ih, W_hh, b_ih, b_hh,
                                               W_out, b_out, out);
}

// Round 5
// 1252.325 us; speedup vs baseline: 1.7834x; 1.5661x over previous
//
#include <hip/hip_runtime.h>

// LSTM, B=512 x T=1024, H=100, input_size=1.
// R1-R4 lesson: the register allocator refuses >128 VGPRs on this toolchain
// (remat at 92, spill at 128/108) regardless of launch_bounds/waves_per_eu.
// So: make the persistent weight set FIT the 128-reg budget instead of
// fighting. Each W_hh row is split across 2 adjacent lanes:
//   even lane: k in [0,52)   (13 float4 from row base)
//   odd  lane: k in [48,100) (13 float4 from row base + 192 B; first 4 zeroed)
// -> 52 weight regs/thread, ~95 total. Partials combine via __shfl_xor(p,1)
// (DPP quad_perm, VALU). The h-window LDS read is one ds_read_b128 with 2
// distinct addresses per wave (2-way broadcast, free; bank sets disjoint).
//
// Block = 896 (14 waves): jobs 0..799 = 400 rows x 2 halves (waves 0..12),
// wave 13 = output-projection wave (Phase C), fully off the Phase-A path.
// Grid = 256 blocks (2 batches per block) -> 1 block/CU, single pass.

#define HID   100
#define TLEN  1024
#define BLOCK 896
#define NJOB  800

__global__ __launch_bounds__(BLOCK) void lstm_split(
    const float* __restrict__ input,   // [B, T]
    const float* __restrict__ W_ih,    // [4H]
    const float* __restrict__ W_hh,    // [4H, H]
    const float* __restrict__ b_ih,    // [4H]
    const float* __restrict__ b_hh,    // [4H]
    const float* __restrict__ W_out,   // [H]
    const float* __restrict__ b_out,   // [1]
    float* __restrict__ out)           // [B, T]
{
    const int b0  = blockIdx.x * 2;
    const int tid = threadIdx.x;

    __shared__ float4 h0_4[26];        // h batch0: 100 floats + pad, 16B-aligned
    __shared__ float4 h1_4[26];        // h batch1
    __shared__ float  g0_s[400];       // gate dot-products, batch0
    __shared__ float  g1_s[400];
    __shared__ float  in0_s[TLEN];
    __shared__ float  in1_s[TLEN];

    float* h0_s = (float*)h0_4;
    float* h1_s = (float*)h1_4;

    // Stage both input rows (8 KB), coalesced.
    for (int i = tid; i < TLEN; i += BLOCK) {
        in0_s[i] = input[(b0 + 0) * TLEN + i];
        in1_s[i] = input[(b0 + 1) * TLEN + i];
    }

    // ---- Phase-A role: thread = (row, half)
    const int row  = (tid < NJOB ? tid : 0) >> 1;   // 0..399
    const int half = tid & 1;
    float4 w[13];                                   // 52 weight regs
    {
        // window base: row*100 floats (400 B, 16-aligned) + half*192 B
        const float4* wp = (const float4*)(W_hh + row * HID + half * 48);
        #pragma unroll
        for (int c = 0; c < 13; ++c) {
            float4 v = wp[c];
            asm volatile("" : "+v"(v.x), "+v"(v.y), "+v"(v.z), "+v"(v.w));
            w[c] = v;
        }
        if (half) { w[0].x = 0.f; w[0].y = 0.f; w[0].z = 0.f; w[0].w = 0.f; }
    }

    // ---- Phase-B role: thread tid<200 -> (batch = tid/100, unit j = tid%100)
    const int pbj = (tid < 200) ? (tid % 100) : 0;
    const float wi0 = W_ih[pbj],        wi1 = W_ih[100 + pbj];
    const float wi2 = W_ih[200 + pbj],  wi3 = W_ih[300 + pbj];
    const float bi0 = b_ih[pbj]       + b_hh[pbj];
    const float bi1 = b_ih[100 + pbj] + b_hh[100 + pbj];
    const float bi2 = b_ih[200 + pbj] + b_hh[200 + pbj];
    const float bi3 = b_ih[300 + pbj] + b_hh[300 + pbj];

    // ---- Phase-C role: wave 13 (tid 832..895), lane l handles h[l], h[64+l]
    const int cl = tid - 832;
    float wo0 = 0.f, wo1 = 0.f, bo = 0.f;
    if (cl >= 0) {
        wo0 = W_out[cl & 63];                         // l<64<100: valid
        wo1 = ((cl & 63) < HID - 64) ? W_out[64 + (cl & 63)] : 0.f;
        bo  = b_out[0];
    }

    float c = 0.f;                     // cell state (Phase-B threads)
    if (tid < 104) { h0_s[tid] = 0.f; h1_s[tid] = 0.f; }
    __syncthreads();

    for (int t = 0; t < TLEN; ++t) {
        // ---- Phase A: half-row dot products, both batches
        if (tid < NJOB) {
            const float4* h0w = ((const float4*)h0_4) + half * 12;  // +48 floats
            const float4* h1w = ((const float4*)h1_4) + half * 12;
            float a0 = 0.f, a1 = 0.f, a2 = 0.f, a3 = 0.f;
            float d0 = 0.f, d1 = 0.f, d2 = 0.f, d3 = 0.f;
            #pragma unroll
            for (int cc = 0; cc < 13; ++cc) {
                float4 ha = h0w[cc];       // 2 addrs/wave -> 2-way broadcast
                float4 hb = h1w[cc];
                float4 wk = w[cc];
                a0 = fmaf(ha.x, wk.x, a0);
                a1 = fmaf(ha.y, wk.y, a1);
                a2 = fmaf(ha.z, wk.z, a2);
                a3 = fmaf(ha.w, wk.w, a3);
                d0 = fmaf(hb.x, wk.x, d0);
                d1 = fmaf(hb.y, wk.y, d1);
                d2 = fmaf(hb.z, wk.z, d2);
                d3 = fmaf(hb.w, wk.w, d3);
            }
            float p0 = (a0 + a1) + (a2 + a3);
            float p1 = (d0 + d1) + (d2 + d3);
            p0 += __shfl_xor(p0, 1, 64);   // combine the two half-rows (DPP)
            p1 += __shfl_xor(p1, 1, 64);
            if (!half) { g0_s[row] = p0; g1_s[row] = p1; }
        }
        __syncthreads();

        // ---- Phase B: pointwise LSTM cell (200 threads: 100 per batch)
        if (tid < 200) {
            const float* gs = (tid < 100) ? g0_s : g1_s;
            float*       hs = (tid < 100) ? h0_s : h1_s;
            const float  x  = (tid < 100) ? in0_s[t] : in1_s[t];
            float ig = fmaf(x, wi0, bi0) + gs[pbj];
            float fg = fmaf(x, wi1, bi1) + gs[100 + pbj];
            float gg = fmaf(x, wi2, bi2) + gs[200 + pbj];
            float og = fmaf(x, wi3, bi3) + gs[300 + pbj];
            float is = 1.f / (1.f + __expf(-ig));
            float fs = 1.f / (1.f + __expf(-fg));
            float os = 1.f / (1.f + __expf(-og));
            float gt = 1.f - 2.f / (__expf(2.f * gg) + 1.f);   // stable tanh
            c = fmaf(fs, c, is * gt);
            float th = 1.f - 2.f / (__expf(2.f * c) + 1.f);
            hs[pbj] = os * th;
        }
        __syncthreads();

        // ---- Phase C: out[b, t] = dot(h, W_out) + b_out  (wave 13, both batches)
        if (cl >= 0) {
            float p = h0_s[cl] * wo0;
            float q = h1_s[cl] * wo0;
            if (cl < HID - 64) {
                p = fmaf(h0_s[64 + cl], wo1, p);
                q = fmaf(h1_s[64 + cl], wo1, q);
            }
            #pragma unroll
            for (int off = 32; off > 0; off >>= 1) {
                p += __shfl_down(p, off);
                q += __shfl_down(q, off);
            }
            if (cl == 0) {
                out[(b0 + 0) * TLEN + t] = p + bo;
                out[(b0 + 1) * TLEN + t] = q + bo;
            }
        }
        // No barrier: Phase C / next Phase A only READ h; the next write to h
        // (Phase B of t+1) is behind the next barrier, which wave 13 also hits.
    }
}

extern "C" void kernel_launch(void* const* d_in, const int* in_sizes, int n_in,
                              void* d_out, int out_size, void* d_ws, size_t ws_size,
                              hipStream_t stream) {
    const float* input = (const float*)d_in[0];
    const float* W_ih  = (const float*)d_in[1];
    const float* W_hh  = (const float*)d_in[2];
    const float* b_ih  = (const float*)d_in[3];
    const float* b_hh  = (const float*)d_in[4];
    const float* W_out = (const float*)d_in[5];
    const float* b_out = (const float*)d_in[6];
    float* out = (float*)d_out;

    const int B = in_sizes[0] / TLEN;  // 512
    lstm_split<<<B / 2, BLOCK, 0, stream>>>(input, W_ih, W_hh, b_ih, b_hh,
                                            W_out, b_out, out);
}